// Round 10
// baseline (142583.630 us; speedup 1.0000x reference)
//
#include <hip/hip_runtime.h>
#include <math.h>

// Problem constants (from reference)
#define NPTS   16384
#define KNN_K  40
#define KCAP   144    // per-wave per-row key buffer
#define KTRIG  128    // compact trigger (per tile append <= 16 -> never overflows)

typedef unsigned short u16;
typedef __attribute__((ext_vector_type(8))) short bf16x8;
typedef __attribute__((ext_vector_type(4))) float f32x4;

// ---- bf16 helpers: fp32 compute, bf16 storage ----
static __device__ __forceinline__ float bf2f(unsigned short h) {
  return __uint_as_float(((unsigned)h) << 16);
}
static __device__ __forceinline__ unsigned short f2bf(float f) {
  unsigned u = __float_as_uint(f);
  unsigned r = (u + 0x7fffu + ((u >> 16) & 1u)) >> 16;   // round-nearest-even
  return (unsigned short)r;
}
static __device__ __forceinline__ float ldf(const float* p) { return *p; }
static __device__ __forceinline__ float ldf(const unsigned short* p) { return bf2f(*p); }
static __device__ __forceinline__ unsigned mbcnt64(unsigned long long m) {
  return __builtin_amdgcn_mbcnt_hi((unsigned)(m >> 32),
                                   __builtin_amdgcn_mbcnt_lo((unsigned)m, 0u));
}

// ---------------------------------------------------------------------------
// MFMA GEMM (dense layers) — unchanged from round 8.
// ---------------------------------------------------------------------------
template<int MCOLS, bool RELU>
__global__ __launch_bounds__(256, 2) void gemm_mfma_k(
    const u16* __restrict__ A1, int lda1,
    const u16* __restrict__ A2, int lda2, int K1,
    const float* __restrict__ W, const float* __restrict__ bias,
    u16* __restrict__ C, int ldc, int K)
{
  constexpr int CT = MCOLS / 64;
  constexpr int AST = 40;
  __shared__ u16 lds[64 * AST + 2 * MCOLS * AST];
  u16* As = lds;
  u16* Wh = lds + 64 * AST;
  u16* Wl = Wh + MCOLS * AST;

  const int tid = threadIdx.x;
  const int lane = tid & 63;
  const int w = tid >> 6;
  const int row0 = blockIdx.x * 64;

  f32x4 acc[4][CT];
  #pragma unroll
  for (int rt = 0; rt < 4; ++rt)
    #pragma unroll
    for (int ct = 0; ct < CT; ++ct)
      acc[rt][ct] = (f32x4){0.f, 0.f, 0.f, 0.f};

  const int rbase = lane & 15;
  const int koff = (lane >> 4) * 8;

  for (int k0 = 0; k0 < K; k0 += 32) {
    __syncthreads();
    {
      int r = tid >> 2, seg = tid & 3;
      int kk = k0 + seg * 8;
      const u16* src = (kk < K1) ? &A1[(size_t)(row0 + r) * lda1 + kk]
                                 : &A2[(size_t)(row0 + r) * lda2 + (kk - K1)];
      *(uint4*)&As[r * AST + seg * 8] = *(const uint4*)src;
    }
    for (int l = tid; l < 32 * MCOLS; l += 256) {
      int n = l & (MCOLS - 1), kk = l / MCOLS;
      float wv = W[(size_t)(k0 + kk) * MCOLS + n];
      u16 h = f2bf(wv);
      Wh[n * AST + kk] = h;
      Wl[n * AST + kk] = f2bf(wv - bf2f(h));
    }
    __syncthreads();

    bf16x8 a[4];
    #pragma unroll
    for (int rt = 0; rt < 4; ++rt)
      a[rt] = *(const bf16x8*)&As[(rt * 16 + rbase) * AST + koff];
    #pragma unroll
    for (int ct = 0; ct < CT; ++ct) {
      int col = (w * CT + ct) * 16 + rbase;
      bf16x8 bh = *(const bf16x8*)&Wh[col * AST + koff];
      bf16x8 bl = *(const bf16x8*)&Wl[col * AST + koff];
      #pragma unroll
      for (int rt = 0; rt < 4; ++rt) {
        acc[rt][ct] = __builtin_amdgcn_mfma_f32_16x16x32_bf16(a[rt], bh, acc[rt][ct], 0, 0, 0);
        acc[rt][ct] = __builtin_amdgcn_mfma_f32_16x16x32_bf16(a[rt], bl, acc[rt][ct], 0, 0, 0);
      }
    }
  }

  __syncthreads();
  constexpr int CST = MCOLS + 8;
  u16* Ct = lds;
  const int rq = (lane >> 4) * 4;
  #pragma unroll
  for (int ct = 0; ct < CT; ++ct) {
    int col = (w * CT + ct) * 16 + rbase;
    float bv = bias[col];
    #pragma unroll
    for (int rt = 0; rt < 4; ++rt) {
      #pragma unroll
      for (int q = 0; q < 4; ++q) {
        float v = acc[rt][ct][q] + bv;
        if (RELU) v = fmaxf(v, 0.f);
        Ct[(rt * 16 + rq + q) * CST + col] = f2bf(v);
      }
    }
  }
  __syncthreads();
  constexpr int SEGS = MCOLS / 8;
  for (int l = tid; l < 64 * SEGS; l += 256) {
    int r = l / SEGS, sg = l % SEGS;
    *(uint4*)&C[(size_t)(row0 + r) * ldc + sg * 8] = *(const uint4*)&Ct[r * CST + sg * 8];
  }
}

// ---------------------------------------------------------------------------
// VALU GEMM (fc1 only: K=9, fp32 input)
// ---------------------------------------------------------------------------
template<int MCOLS, bool RELU, typename TIN, typename TOUT>
__global__ __launch_bounds__(256, 4) void gemm_k(
    const TIN* __restrict__ A1, int lda1,
    const TIN* __restrict__ A2, int lda2, int K1,
    const float* __restrict__ W, const float* __restrict__ bias,
    TOUT* __restrict__ C, int ldc, int K)
{
  constexpr int TCS = MCOLS / 8;
  constexpr int RPT = (64 * TCS) / 256;
  __shared__ float Asl[64][33];
  __shared__ float Ws[32][MCOLS];
  const int tid = threadIdx.x;
  const int row0 = blockIdx.x * 64;
  const int tc = tid % TCS, tr = tid / TCS;

  float acc[RPT][8];
  #pragma unroll
  for (int p = 0; p < RPT; ++p)
    #pragma unroll
    for (int q = 0; q < 8; ++q) acc[p][q] = 0.f;

  for (int k0 = 0; k0 < K; k0 += 32) {
    __syncthreads();
    for (int l = tid; l < 64 * 32; l += 256) {
      int r = l >> 5, c = l & 31, k = k0 + c;
      float v = 0.f;
      if (k < K) v = (k < K1) ? ldf(&A1[(size_t)(row0 + r) * lda1 + k])
                              : ldf(&A2[(size_t)(row0 + r) * lda2 + (k - K1)]);
      Asl[r][c] = v;
    }
    for (int l = tid; l < 32 * MCOLS; l += 256) {
      int kr = l / MCOLS, c = l % MCOLS, k = k0 + kr;
      Ws[kr][c] = (k < K) ? W[(size_t)k * MCOLS + c] : 0.f;
    }
    __syncthreads();
    #pragma unroll
    for (int kk = 0; kk < 32; ++kk) {
      float a[RPT];
      #pragma unroll
      for (int p = 0; p < RPT; ++p) a[p] = Asl[tr * RPT + p][kk];
      const float4 w0 = *(const float4*)&Ws[kk][tc * 8];
      const float4 w1 = *(const float4*)&Ws[kk][tc * 8 + 4];
      #pragma unroll
      for (int p = 0; p < RPT; ++p) {
        acc[p][0] = fmaf(a[p], w0.x, acc[p][0]);
        acc[p][1] = fmaf(a[p], w0.y, acc[p][1]);
        acc[p][2] = fmaf(a[p], w0.z, acc[p][2]);
        acc[p][3] = fmaf(a[p], w0.w, acc[p][3]);
        acc[p][4] = fmaf(a[p], w1.x, acc[p][4]);
        acc[p][5] = fmaf(a[p], w1.y, acc[p][5]);
        acc[p][6] = fmaf(a[p], w1.z, acc[p][6]);
        acc[p][7] = fmaf(a[p], w1.w, acc[p][7]);
      }
    }
  }

  const float4 b0 = *(const float4*)&bias[tc * 8];
  const float4 b1 = *(const float4*)&bias[tc * 8 + 4];
  #pragma unroll
  for (int p = 0; p < RPT; ++p) {
    int r = row0 + tr * RPT + p;
    float o[8];
    o[0] = acc[p][0] + b0.x; o[1] = acc[p][1] + b0.y;
    o[2] = acc[p][2] + b0.z; o[3] = acc[p][3] + b0.w;
    o[4] = acc[p][4] + b1.x; o[5] = acc[p][5] + b1.y;
    o[6] = acc[p][6] + b1.z; o[7] = acc[p][7] + b1.w;
    if (RELU) {
      #pragma unroll
      for (int q = 0; q < 8; ++q) o[q] = fmaxf(o[q], 0.f);
    }
    if constexpr (sizeof(TOUT) == 2) {
      unsigned p0 = (unsigned)f2bf(o[0]) | ((unsigned)f2bf(o[1]) << 16);
      unsigned p1 = (unsigned)f2bf(o[2]) | ((unsigned)f2bf(o[3]) << 16);
      unsigned p2 = (unsigned)f2bf(o[4]) | ((unsigned)f2bf(o[5]) << 16);
      unsigned p3 = (unsigned)f2bf(o[6]) | ((unsigned)f2bf(o[7]) << 16);
      uint4 pk = make_uint4(p0, p1, p2, p3);
      *(uint4*)&C[(size_t)r * ldc + tc * 8] = pk;
    } else {
      float4 o0, o1;
      o0.x = o[0]; o0.y = o[1]; o0.z = o[2]; o0.w = o[3];
      o1.x = o[4]; o1.y = o[5]; o1.z = o[6]; o1.w = o[7];
      *(float4*)&C[(size_t)r * ldc + tc * 8] = o0;
      *(float4*)&C[(size_t)r * ldc + tc * 8 + 4] = o1;
    }
  }
}

// ---------------------------------------------------------------------------
// Small-M GEMM (M = 4): lin_s (VV=true also emits the 16-bf16 MFMA distance
// operand vectors Va/Vb per point) and fc4.
//  Va = [-2shi(4), -2shi(4), -2slo(4), s2h, s2l, 1, 1]
//  Vb = [ shi(4),   slo(4),   shi(4),  1, 1, s2h, s2l]
//  dot(Va_i, Vb_j) = |si|^2 + |sj|^2 - 2(shi.shj + shi.sloj + sloi.shj)
// ---------------------------------------------------------------------------
template<bool RELU, bool VV, typename TOUT>
__global__ __launch_bounds__(256, 4) void gemm4_k(
    const u16* __restrict__ A, int lda,
    const float* __restrict__ W, const float* __restrict__ bias,
    TOUT* __restrict__ C, int K, u16* Va, u16* Vb)
{
  __shared__ float Wsl[128 * 4];
  __shared__ float bl[4];
  const int tid = threadIdx.x;
  for (int l = tid; l < K * 4; l += 256) Wsl[l] = W[l];
  if (tid < 4) bl[tid] = bias[tid];
  __syncthreads();
  const int row = blockIdx.x * 256 + tid;
  const u16* ap = A + (size_t)row * lda;
  float a0 = bl[0], a1 = bl[1], a2 = bl[2], a3 = bl[3];
  for (int k8 = 0; k8 < K; k8 += 8) {
    uint4 pk = *(const uint4*)&ap[k8];
    unsigned uu[4] = {pk.x, pk.y, pk.z, pk.w};
    #pragma unroll
    for (int q = 0; q < 4; ++q) {
      float flo = __uint_as_float(uu[q] << 16);
      float fhi = __uint_as_float(uu[q] & 0xFFFF0000u);
      const float* wr0 = &Wsl[(k8 + 2 * q) * 4];
      a0 = fmaf(flo, wr0[0], a0); a1 = fmaf(flo, wr0[1], a1);
      a2 = fmaf(flo, wr0[2], a2); a3 = fmaf(flo, wr0[3], a3);
      a0 = fmaf(fhi, wr0[4], a0); a1 = fmaf(fhi, wr0[5], a1);
      a2 = fmaf(fhi, wr0[6], a2); a3 = fmaf(fhi, wr0[7], a3);
    }
  }
  if (RELU) {
    a0 = fmaxf(a0, 0.f); a1 = fmaxf(a1, 0.f);
    a2 = fmaxf(a2, 0.f); a3 = fmaxf(a3, 0.f);
  }
  if constexpr (sizeof(TOUT) == 2) {
    C[(size_t)row * 4 + 0] = (TOUT)f2bf(a0);
    C[(size_t)row * 4 + 1] = (TOUT)f2bf(a1);
    C[(size_t)row * 4 + 2] = (TOUT)f2bf(a2);
    C[(size_t)row * 4 + 3] = (TOUT)f2bf(a3);
  } else {
    float4 o; o.x = a0; o.y = a1; o.z = a2; o.w = a3;
    *(float4*)&C[(size_t)row * 4] = o;
  }
  if constexpr (VV) {
    float s[4] = {a0, a1, a2, a3};
    u16 h[4], l[4], nh[4], nl[4];
    #pragma unroll
    for (int d = 0; d < 4; ++d) {
      h[d] = f2bf(s[d]);
      l[d] = f2bf(s[d] - bf2f(h[d]));
      nh[d] = f2bf(-2.f * bf2f(h[d]));
      nl[d] = f2bf(-2.f * bf2f(l[d]));
    }
    float s2 = fmaf(a0, a0, fmaf(a1, a1, fmaf(a2, a2, a3 * a3)));
    u16 s2h = f2bf(s2), s2l = f2bf(s2 - bf2f(s2h));
    const u16 one = 0x3F80;
    #define PK2(x, y) ((unsigned)(x) | ((unsigned)(y) << 16))
    uint4 va0 = make_uint4(PK2(nh[0], nh[1]), PK2(nh[2], nh[3]),
                           PK2(nh[0], nh[1]), PK2(nh[2], nh[3]));
    uint4 va1 = make_uint4(PK2(nl[0], nl[1]), PK2(nl[2], nl[3]),
                           PK2(s2h, s2l), PK2(one, one));
    uint4 vb0 = make_uint4(PK2(h[0], h[1]), PK2(h[2], h[3]),
                           PK2(l[0], l[1]), PK2(l[2], l[3]));
    uint4 vb1 = make_uint4(PK2(h[0], h[1]), PK2(h[2], h[3]),
                           PK2(one, one), PK2(s2h, s2l));
    #undef PK2
    *(uint4*)&Va[(size_t)row * 16] = va0;
    *(uint4*)&Va[(size_t)row * 16 + 8] = va1;
    *(uint4*)&Vb[(size_t)row * 16] = vb0;
    *(uint4*)&Vb[(size_t)row * 16 + 8] = vb1;
  }
}

// ---------------------------------------------------------------------------
// kNN v8: MFMA distance tiles + accumulator-side filtering.
// Block = 4 waves = 16 rows (grid 1024). Wave w scans candidate slice
// [w*4096, (w+1)*4096). Phase 1: min3 per (lane,reg) -> 16-row simultaneous
// wave bisect -> thr0 >= slice-40th >= global-40th (capped count <= true
// count: monotone, exact-safe). Phase 2: rescan slice, filter acc vs thr,
// ballot-prefix append (~50-70/row, compaction ~never). Merge 4 slices,
// compact <=96 (inflated keep-threshold covers bf16 error), exact fp32
// recompute, bitonic-128, emit top-40. Stored keys carry a 1.004 margin and
// the filter threshold a 1.002 margin so no true neighbor is ever dropped.
// ---------------------------------------------------------------------------
struct CompactRes { int cnt; unsigned thr; };

static __device__ __forceinline__ CompactRes compact_kb(unsigned* bufR, int cnt,
                                                        int lane, int cap) {
  int n = min(cnt, cap);
  int lo = -1, hi = 0x7FFFFFFF, chi = n;
  for (int it = 0; it < 32; ++it) {
    if (chi <= 90) break;
    int mid = lo + ((hi - lo) >> 1);
    int lc = 0;
    for (int base = 0; base < n; base += 64) {
      int i = base + lane;
      bool c = (i < n) && (bufR[i] <= (unsigned)mid);
      lc += (int)__popcll(__ballot(c));
    }
    if (lc >= 40) { hi = mid; chi = lc; } else lo = mid;
  }
  unsigned thr = (unsigned)hi;
  // inflated keep-threshold (preserves exactness under bf16-MFMA error)
  unsigned thrK = thr;
  if (thr != 0x7FFFFFFFu) {
    float tf = __uint_as_float((thr & 0xFFFFC000u) | 0x3FFFu) * 1.003f;
    thrK = (__float_as_uint(tf) & 0xFFFFC000u) | 0x3FFFu;
  }
  int out = 0;
  for (int base = 0; base < n; base += 64) {
    int i = base + lane;
    unsigned key = (i < n) ? bufR[i] : 0xFFFFFFFFu;
    bool keep = (i < n) && (key <= thrK);
    unsigned long long mk = __ballot(keep);
    unsigned pre = mbcnt64(mk);
    if (keep) bufR[out + (int)pre] = key;
    out += (int)__popcll(mk);
  }
  CompactRes r; r.cnt = out; r.thr = thr;
  return r;
}

__global__ __launch_bounds__(256, 3) void knn_k(
    const u16* __restrict__ Va, const u16* __restrict__ Vb,
    const float4* __restrict__ s4,
    u16* __restrict__ idx_out, u16* __restrict__ w_out)
{
  __shared__ unsigned buf[4][16][KCAP];
  __shared__ unsigned scr[4][576];
  __shared__ int cnt_lds[4][16];

  const int tid = threadIdx.x;
  const int lane = tid & 63;
  const int w = tid >> 6;
  const int m = lane & 15;
  const int quad = lane >> 4;
  const int qs = quad * 16;
  const int sp0 = blockIdx.x * 16;
  const int cw0 = w * 4096;
  const f32x4 zero = {0.f, 0.f, 0.f, 0.f};

  // A-fragment: row = sp0 + m, k-chunk = quad*8 (quads 2,3 = zero padding)
  bf16x8 af = (bf16x8)(short)0;
  if (quad < 2) af = *(const bf16x8*)&Va[(size_t)(sp0 + m) * 16 + quad * 8];

  // ---- phase 1: min3 over the wave's slice ----
  float m1[4], m2[4], m3[4];
  #pragma unroll
  for (int r = 0; r < 4; ++r) { m1[r] = 3e38f; m2[r] = 3e38f; m3[r] = 3e38f; }
  for (int t = 0; t < 256; ++t) {
    int cb = cw0 + t * 16;
    bf16x8 bf = (bf16x8)(short)0;
    if (quad < 2) bf = *(const bf16x8*)&Vb[(size_t)(cb + m) * 16 + quad * 8];
    f32x4 d = __builtin_amdgcn_mfma_f32_16x16x32_bf16(af, bf, zero, 0, 0, 0);
    #pragma unroll
    for (int r = 0; r < 4; ++r) {
      float v = fmaxf(d[r], 0.f);
      float t1 = fmaxf(m1[r], v);
      m1[r] = fminf(m1[r], v);
      float t2 = fmaxf(m2[r], t1);
      m2[r] = fminf(m2[r], t1);
      m3[r] = fminf(m3[r], t2);
    }
  }

  // ---- 16-row simultaneous bisect (capped count >= 40 -> thr0 safe) ----
  float thrF[4];
  {
    int lo_[4], hi_[4];
    #pragma unroll
    for (int r = 0; r < 4; ++r) { lo_[r] = -1; hi_[r] = 0x7F800000; }
    for (int it = 0; it < 20; ++it) {
      #pragma unroll
      for (int r = 0; r < 4; ++r) {
        if (hi_[r] - lo_[r] <= 1) continue;
        int mid = lo_[r] + ((hi_[r] - lo_[r]) >> 1);
        float mf = __uint_as_float((unsigned)mid);
        unsigned long long b1 = __ballot(m1[r] <= mf);
        unsigned long long b2 = __ballot(m2[r] <= mf);
        unsigned long long b3 = __ballot(m3[r] <= mf);
        int c = __builtin_popcount((unsigned)(b1 >> qs) & 0xFFFFu)
              + __builtin_popcount((unsigned)(b2 >> qs) & 0xFFFFu)
              + __builtin_popcount((unsigned)(b3 >> qs) & 0xFFFFu);
        if (c >= 40) hi_[r] = mid; else lo_[r] = mid;
      }
    }
    #pragma unroll
    for (int r = 0; r < 4; ++r)
      thrF[r] = __uint_as_float((unsigned)hi_[r]) * 1.002f;
  }

  // ---- phase 2: rescan slice with filter + append ----
  int cnt[4] = {0, 0, 0, 0};
  for (int t = 0; t < 256; ++t) {
    int cb = cw0 + t * 16;
    bf16x8 bf = (bf16x8)(short)0;
    if (quad < 2) bf = *(const bf16x8*)&Vb[(size_t)(cb + m) * 16 + quad * 8];
    f32x4 d = __builtin_amdgcn_mfma_f32_16x16x32_bf16(af, bf, zero, 0, 0, 0);
    #pragma unroll
    for (int r = 0; r < 4; ++r) {
      bool keep = d[r] <= thrF[r];
      unsigned long long um = __ballot(keep);
      if (um) {
        unsigned q16 = (unsigned)(um >> qs) & 0xFFFFu;
        int pos = cnt[r] + __builtin_popcount(q16 & ((1u << m) - 1u));
        if (keep && pos < KCAP) {
          float du = fmaxf(d[r], 0.f) * 1.004f;
          buf[w][quad * 4 + r][pos] =
              (__float_as_uint(du) & 0xFFFFC000u) | (unsigned)(cb + m);
        }
        cnt[r] = min(cnt[r] + __builtin_popcount(q16), KCAP);
      }
    }
    int cmax = max(max(cnt[0], cnt[1]), max(cnt[2], cnt[3]));
    if (__ballot(cmax >= KTRIG)) {
      #pragma unroll
      for (int r = 0; r < 4; ++r) {
        unsigned long long bm = __ballot(cnt[r] >= KTRIG);
        #pragma unroll
        for (int q = 0; q < 4; ++q) {
          if ((unsigned)(bm >> (q * 16)) & 0xFFFFu) {
            int c0 = __shfl(cnt[r], q * 16, 64);
            CompactRes cr = compact_kb(&buf[w][q * 4 + r][0], c0, lane, KCAP);
            if (quad == q) {
              cnt[r] = cr.cnt;
              thrF[r] = __uint_as_float((cr.thr & 0xFFFFC000u) | 0x3FFFu);
            }
          }
        }
      }
    }
  }

  // ---- publish counts, merge 4 slices per row ----
  if (m == 0) {
    #pragma unroll
    for (int r = 0; r < 4; ++r) cnt_lds[w][quad * 4 + r] = cnt[r];
  }
  __syncthreads();

  #pragma unroll
  for (int rr = 0; rr < 4; ++rr) {
    const int r = w * 4 + rr;
    int tot = 0;
    #pragma unroll
    for (int v = 0; v < 4; ++v) {
      int c = cnt_lds[v][r];
      for (int i = lane; i < c; i += 64) scr[w][tot + i] = buf[v][r][i];
      tot += c;
    }
    CompactRes cr = compact_kb(scr[w], tot, lane, 576);
    int mN = min(cr.cnt, 128);

    const int row = sp0 + r;
    float4 si = s4[row];
    const float fx = -2.f * si.x, fy = -2.f * si.y;
    const float fz = -2.f * si.z, fw = -2.f * si.w;
    const float s2i = fmaf(si.x, si.x, fmaf(si.y, si.y, fmaf(si.z, si.z, si.w * si.w)));

    unsigned long long e0 = ~0ull, e1 = ~0ull;
    {
      int sl0 = lane * 2, sl1 = lane * 2 + 1;
      if (sl0 < mN) {
        unsigned idx = scr[w][sl0] & 0x3FFFu;
        float4 p = s4[idx];
        float qj = fmaf(p.x, p.x, fmaf(p.y, p.y, fmaf(p.z, p.z, p.w * p.w)));
        float d = fmaf(fx, p.x, fmaf(fy, p.y, fmaf(fz, p.z, fmaf(fw, p.w, qj + s2i))));
        e0 = (((unsigned long long)__float_as_uint(fmaxf(d, 0.f))) << 32) | idx;
      }
      if (sl1 < mN) {
        unsigned idx = scr[w][sl1] & 0x3FFFu;
        float4 p = s4[idx];
        float qj = fmaf(p.x, p.x, fmaf(p.y, p.y, fmaf(p.z, p.z, p.w * p.w)));
        float d = fmaf(fx, p.x, fmaf(fy, p.y, fmaf(fz, p.z, fmaf(fw, p.w, qj + s2i))));
        e1 = (((unsigned long long)__float_as_uint(fmaxf(d, 0.f))) << 32) | idx;
      }
    }

    #pragma unroll
    for (int k = 2; k <= 128; k <<= 1) {
      #pragma unroll
      for (int jj = k >> 1; jj >= 1; jj >>= 1) {
        bool up = (((lane * 2) & k) == 0);
        if (jj == 1) {
          unsigned long long a = (e0 < e1) ? e0 : e1;
          unsigned long long b = (e0 < e1) ? e1 : e0;
          e0 = up ? a : b; e1 = up ? b : a;
        } else {
          int lj = jj >> 1;
          bool lower = ((lane & lj) == 0);
          bool tm = (up == lower);
          unsigned long long o0 = __shfl_xor(e0, lj, 64);
          e0 = tm ? ((e0 < o0) ? e0 : o0) : ((e0 > o0) ? e0 : o0);
          unsigned long long o1 = __shfl_xor(e1, lj, 64);
          e1 = tm ? ((e1 < o1) ? e1 : o1) : ((e1 > o1) ? e1 : o1);
        }
      }
    }

    const int ob = row * KNN_K;
    if (lane < 20) {
      int v0 = lane * 2;
      idx_out[ob + v0] = (unsigned short)(e0 & 0xFFFFu);
      w_out[ob + v0] = f2bf(__expf(-10.f * __uint_as_float((unsigned)(e0 >> 32))));
      int v1 = v0 + 1;
      idx_out[ob + v1] = (unsigned short)(e1 & 0xFFFFu);
      w_out[ob + v1] = f2bf(__expf(-10.f * __uint_as_float((unsigned)(e1 >> 32))));
    }
  }
}

// ---------------------------------------------------------------------------
// Aggregation: Aout[i] = [mean_k h[idx]*w | max_k h[idx]*w]  (N x 128, bf16).
// ---------------------------------------------------------------------------
__global__ __launch_bounds__(256, 4) void agg_k(
    const unsigned short* __restrict__ h, const unsigned short* __restrict__ idxb,
    const unsigned short* __restrict__ wb, unsigned short* __restrict__ Aout)
{
  const int row = blockIdx.x * 4 + (threadIdx.x >> 6);
  const int lane = threadIdx.x & 63;
  const int base = row * KNN_K;
  float mean = 0.f, mx = -INFINITY;
  #pragma unroll 4
  for (int k = 0; k < KNN_K; ++k) {
    int j = idxb[base + k];
    float wv = bf2f(wb[base + k]);
    float m = bf2f(h[(size_t)j * 64 + lane]) * wv;
    mean += m;
    mx = fmaxf(mx, m);
  }
  Aout[(size_t)row * 128 + lane] = f2bf(mean * (1.f / 40.f));
  Aout[(size_t)row * 128 + 64 + lane] = f2bf(mx);
}

// ---------------------------------------------------------------------------
extern "C" void kernel_launch(void* const* d_in, const int* in_sizes, int n_in,
                              void* d_out, int out_size, void* d_ws, size_t ws_size,
                              hipStream_t stream)
{
  const float* x    = (const float*)d_in[0];
  const float* fc1W = (const float*)d_in[1];  const float* fc1b = (const float*)d_in[2];
  const float* fc2W = (const float*)d_in[3];  const float* fc2b = (const float*)d_in[4];
  const float* gsW  = (const float*)d_in[5];  const float* gsb  = (const float*)d_in[6];
  const float* ghW  = (const float*)d_in[7];  const float* ghb  = (const float*)d_in[8];
  const float* goW  = (const float*)d_in[9];  const float* gob  = (const float*)d_in[10];
  const float* d1W  = (const float*)d_in[11]; const float* d1b  = (const float*)d_in[12];
  const float* d2W  = (const float*)d_in[13]; const float* d2b  = (const float*)d_in[14];
  const float* d3W  = (const float*)d_in[15]; const float* d3b  = (const float*)d_in[16];
  const float* fc3W = (const float*)d_in[17]; const float* fc3b = (const float*)d_in[18];
  const float* fc4W = (const float*)d_in[19]; const float* fc4b = (const float*)d_in[20];
  float* out = (float*)d_out;

  // ---- workspace layout (~14.5 MiB) ----
  const size_t N = NPTS;
  u16* X    = (u16*)d_ws;                 // N*128 bf16
  u16* Abuf = X + N * 128;                // N*128 bf16 (fp32 S aliased at start)
  u16* T    = Abuf + N * 128;             // N*128 bf16 (bf16 H aliased at start)
  u16* IDX  = T + N * 128;                // N*40 u16
  u16* WNB  = IDX + N * 40;               // N*40 bf16
  u16* Vag  = WNB + N * 40;               // N*16 bf16 (MFMA A-vectors)
  u16* Vbg  = Vag + N * 16;               // N*16 bf16 (MFMA B-vectors)
  float* S = (float*)Abuf;                // N*4 fp32 (lin_s output)
  u16* H = T;                             // N*64 bf16

  gemm_k<128, true, float, u16><<<NPTS / 64, 256, 0, stream>>>(
      x, 9, x, 9, 9, fc1W, fc1b, T, 128, 9);
  gemm_mfma_k<128, true><<<NPTS / 64, 256, 0, stream>>>(
      T, 128, T, 128, 128, fc2W, fc2b, X, 128, 128);

  for (int l = 0; l < 4; ++l) {
    gemm4_k<false, true, float><<<NPTS / 256, 256, 0, stream>>>(
        X, 128, gsW + l * 128 * 4, gsb + l * 4, S, 128, Vag, Vbg);
    gemm_mfma_k<64, false><<<NPTS / 64, 256, 0, stream>>>(
        X, 128, X, 128, 128, ghW + l * 128 * 64, ghb + l * 64, H, 64, 128);
    knn_k<<<NPTS / 16, 256, 0, stream>>>(Vag, Vbg, (const float4*)S, IDX, WNB);
    agg_k<<<NPTS / 4, 256, 0, stream>>>(H, IDX, WNB, Abuf);
    gemm_mfma_k<128, false><<<NPTS / 64, 256, 0, stream>>>(
        X, 128, Abuf, 128, 128, goW + l * 256 * 128, gob + l * 128, T, 128, 256);
    gemm_mfma_k<128, true><<<NPTS / 64, 256, 0, stream>>>(
        T, 128, T, 128, 128, d1W + l * 128 * 128, d1b + l * 128, Abuf, 128, 128);
    gemm_mfma_k<128, true><<<NPTS / 64, 256, 0, stream>>>(
        Abuf, 128, Abuf, 128, 128, d2W + l * 128 * 128, d2b + l * 128, T, 128, 128);
    gemm_mfma_k<128, true><<<NPTS / 64, 256, 0, stream>>>(
        T, 128, T, 128, 128, d3W + l * 128 * 128, d3b + l * 128, X, 128, 128);
  }

  gemm_mfma_k<128, true><<<NPTS / 64, 256, 0, stream>>>(
      X, 128, X, 128, 128, fc3W, fc3b, T, 128, 128);
  gemm4_k<false, false, float><<<NPTS / 256, 256, 0, stream>>>(
      T, 128, fc4W, fc4b, out, 128, nullptr, nullptr);
}